// Round 2
// baseline (300.667 us; speedup 1.0000x reference)
//
#include <hip/hip_runtime.h>

// Attention_Critic on MI355X — round 11: de-stall k_enc3 -> k_enc4.
//  - k_prep: unchanged.
//  - k_fin (new, 8 blocks): folds BN stats partials into mst_g once, removing the
//    per-block 32-iteration serial reduction that every enc block paid.
//  - k_enc4 (was k_enc3): identical math/dataflow (E LDS-transient; SE/SEL/KEY/VAL
//    to global), but ALL global stores now go LDS-tile -> coalesced short8 stores
//    (16 wide stores/thread instead of 128 scalar u16), batched at barriers so
//    store-acks never sit in front of dependent loads in the vmcnt FIFO. A-frags
//    hoisted to registers and reused across heads; head loops unrolled.
//  - k_attn, k_critic: byte-identical to round 10.
//
// ws layout (bytes):
//   [0,256)        int flag (1 = bf16 inputs, 0 = f32)
//   [256,+163840)  stats partials f32 [8][32][80][2]
//   [164096,+5120) mst_g f32 [8][80][2]  (mean, rstd)
//   [169216,...)   Wsa_t bf16 [8][128 col][104 k]
//   [382208,...)   Wse_t bf16 [8][128 col][72 k]
//   [529664,...)   Wp_t  bf16 [4 p][3 mat][32 d][136 k]  (mat 0=sel,1=key,2=val)
//   [634112,...)   Wc1t  bf16 [8][128 col][256 k]
//   [1158400,+32M) SE  bf16 [8][16384][128]
//   [+32M,+64M)    SEL bf16 [8][16384][128]   (4 heads x 32)
//   [+64M,+96M)    KEY bf16 [8][16384][128]
//   [+96M,+128M)   VAL bf16 [8][16384][128]
//   [+128M,+160M)  OT  bf16 [8][16384][128]

typedef unsigned short u16;
typedef unsigned int u32;

#define NA 8
#define BATCH 16384
#define SD 64
#define AD 16
#define IND 80
#define HID 128
#define HEADS 4
#define ATT 32
#define EPS 1e-5f
#define KP 136    // u16 stride, 128-k tiles
#define KP3 104   // u16 stride, 96-k tiles (Wsa_t)
#define KPS 72    // u16 stride, 64-k tiles (Wse_t)
#define VTS 68    // u16 stride, valt [32 d][64 row']
#define WBS 24    // u16 stride, softmax weight tiles

using short8 = __attribute__((ext_vector_type(8))) short;
using float4f = __attribute__((ext_vector_type(4))) float;
#define MFMA16(a, b, c) __builtin_amdgcn_mfma_f32_16x16x32_bf16((a), (b), (c), 0, 0, 0)

__device__ __forceinline__ float bf2f(u16 u) { union { u32 i; float f; } v; v.i = ((u32)u) << 16; return v.f; }
__device__ __forceinline__ float lo2f(u32 w) { union { u32 i; float f; } v; v.i = w << 16; return v.f; }
__device__ __forceinline__ float hi2f(u32 w) { union { u32 i; float f; } v; v.i = w & 0xffff0000u; return v.f; }
__device__ __forceinline__ u16 f2bf(float f) {
  union { float f; u32 i; } v; v.f = f;
  u32 x = v.i;
  x += 0x7fffu + ((x >> 16) & 1u);   // RNE
  return (u16)(x >> 16);
}
__device__ __forceinline__ float lrelu(float x) { return x > 0.f ? x : 0.01f * x; }
__device__ __forceinline__ float ldin(const void* p, size_t i, bool bf) {
  return bf ? bf2f(((const u16*)p)[i]) : ((const float*)p)[i];
}
__device__ __forceinline__ u16 ldbf(const void* p, size_t i, bool bf) {
  return bf ? ((const u16*)p)[i] : f2bf(((const float*)p)[i]);
}
__device__ __forceinline__ short8 lds_s8(const u16* p) {   // 16B LDS load, 4B-aligned ok
  union { short8 v; u32 u[4]; } t;
  const u32* q = (const u32*)p;
  t.u[0] = q[0]; t.u[1] = q[1]; t.u[2] = q[2]; t.u[3] = q[3];
  return t.v;
}

// ---------------- K1: merged BN stats + weight prep (per-block dtype detect) ----------------
// blocks [0,256): stats; [256,288): Wc1; [288,296): Wsa; [296,304): Wse; [304,316): Wp.
__global__ __launch_bounds__(256) void k_prep(
    const void* __restrict__ s, const void* __restrict__ a,
    const void* __restrict__ Wsa, const void* __restrict__ Wse,
    const void* __restrict__ Wsl, const void* __restrict__ Wk, const void* __restrict__ Wv,
    const void* __restrict__ Wc1,
    int* __restrict__ flag, float* __restrict__ part,
    u16* __restrict__ Wsa_t, u16* __restrict__ Wse_t, u16* __restrict__ Wp_t, u16* __restrict__ Wc1t) {
  __shared__ u16 T[80 * 130];
  __shared__ float S0[256], Q0[256], S1[256], Q1[256];
  __shared__ int cnt[2];
  int tid = threadIdx.x;
  if (tid < 2) cnt[tid] = 0;
  __syncthreads();
  {   // local dtype detection (all blocks)
    u32 wv = ((const u32*)s)[tid];
    u32 lo = wv & 0xffffu, e = (lo >> 7) & 0xffu;
    if (lo == 0u || lo == 0x8000u) atomicAdd(&cnt[1], 1);
    else if (e < 0x70u || e > 0x8fu) atomicAdd(&cnt[0], 1);
  }
  __syncthreads();
  bool bf = !(cnt[0] >= 64 || cnt[1] >= 192);
  if (blockIdx.x == 0 && tid == 0) *flag = bf ? 1 : 0;
  int blkr = blockIdx.x;
  if (blkr < 256) {   // ---- stats ----
    int blk = blkr, n = blk >> 5, c = blk & 31, b0 = c << 9;
    {
      int f2 = tid & 31, rg = tid >> 5;
      float s0 = 0.f, s1 = 0.f, q0 = 0.f, q1 = 0.f;
      for (int i = 0; i < 64; i++) {
        int b = b0 + rg + 8 * i;
        float x0, x1;
        if (bf) { u32 wv = ((const u32*)s)[((size_t)n * BATCH + b) * 32 + f2]; x0 = lo2f(wv); x1 = hi2f(wv); }
        else { const float* sf = (const float*)s + ((size_t)n * BATCH + b) * 64 + 2 * f2; x0 = sf[0]; x1 = sf[1]; }
        s0 += x0; q0 += x0 * x0; s1 += x1; q1 += x1 * x1;
      }
      S0[tid] = s0; Q0[tid] = q0; S1[tid] = s1; Q1[tid] = q1;
    }
    __syncthreads();
    if (tid < 64) {
      int f2 = tid >> 1, odd = tid & 1;
      float S = 0.f, Q = 0.f;
      for (int rg = 0; rg < 8; rg++) {
        int ix = rg * 32 + f2;
        S += odd ? S1[ix] : S0[ix];
        Q += odd ? Q1[ix] : Q0[ix];
      }
      float* p = part + ((size_t)blk * IND + tid) * 2;
      p[0] = S; p[1] = Q;
    }
    __syncthreads();
    {
      int f2 = tid & 7, rg = tid >> 3;
      float s0 = 0.f, s1 = 0.f, q0 = 0.f, q1 = 0.f;
      for (int i = 0; i < 16; i++) {
        int b = b0 + rg + 32 * i;
        float x0, x1;
        if (bf) { u32 wv = ((const u32*)a)[((size_t)n * BATCH + b) * 8 + f2]; x0 = lo2f(wv); x1 = hi2f(wv); }
        else { const float* af = (const float*)a + ((size_t)n * BATCH + b) * 16 + 2 * f2; x0 = af[0]; x1 = af[1]; }
        s0 += x0; q0 += x0 * x0; s1 += x1; q1 += x1 * x1;
      }
      S0[tid] = s0; Q0[tid] = q0; S1[tid] = s1; Q1[tid] = q1;
    }
    __syncthreads();
    if (tid < 16) {
      int f2 = tid >> 1, odd = tid & 1;
      float S = 0.f, Q = 0.f;
      for (int rg = 0; rg < 32; rg++) {
        int ix = rg * 8 + f2;
        S += odd ? S1[ix] : S0[ix];
        Q += odd ? Q1[ix] : Q0[ix];
      }
      float* p = part + ((size_t)blk * IND + SD + tid) * 2;
      p[0] = S; p[1] = Q;
    }
    return;
  }
  int blk = blkr - 256;   // ---- weight prep ----
  if (blk < 32) {                       // Wc1 [n][256][128] -> Wc1t [n][128][256]
    int n = blk >> 2, k0 = (blk & 3) * 64;
    for (int i = tid; i < 64 * 128; i += 256) {
      int kr = i >> 7, cc = i & 127;
      T[kr * 130 + cc] = ldbf(Wc1, ((size_t)n * 256 + k0 + kr) * 128 + cc, bf);
    }
    __syncthreads();
    for (int i = tid; i < 128 * 64; i += 256) {
      int col = i >> 6, kk = i & 63;
      Wc1t[((size_t)n * 128 + col) * 256 + k0 + kk] = T[kk * 130 + col];
    }
  } else if (blk < 40) {                // Wsa -> Wsa_t
    int n = blk - 32;
    for (int i = tid; i < 80 * 128; i += 256) {
      int kr = i >> 7, cc = i & 127;
      T[kr * 130 + cc] = ldbf(Wsa, ((size_t)n * IND + kr) * 128 + cc, bf);
    }
    __syncthreads();
    for (int i = tid; i < 128 * KP3; i += 256) {
      int col = i / KP3, k = i - col * KP3;
      Wsa_t[((size_t)n * 128 + col) * KP3 + k] = (k < IND) ? T[k * 130 + col] : (u16)0;
    }
  } else if (blk < 48) {                // Wse -> Wse_t
    int n = blk - 40;
    for (int i = tid; i < 64 * 128; i += 256) {
      int kr = i >> 7, cc = i & 127;
      T[kr * 130 + cc] = ldbf(Wse, ((size_t)n * SD + kr) * 128 + cc, bf);
    }
    __syncthreads();
    for (int i = tid; i < 128 * KPS; i += 256) {
      int col = i / KPS, k = i - col * KPS;
      Wse_t[((size_t)n * 128 + col) * KPS + k] = (k < SD) ? T[k * 130 + col] : (u16)0;
    }
  } else {                              // Wp -> Wp_t
    int pm = blk - 48, p = pm / 3, mat = pm - 3 * p;
    const void* W = (mat == 0) ? Wsl : (mat == 1) ? Wk : Wv;
    for (int i = tid; i < 128 * 32; i += 256) {
      int kr = i >> 5, d = i & 31;
      T[kr * 34 + d] = ldbf(W, ((size_t)p * HID + kr) * ATT + d, bf);
    }
    __syncthreads();
    for (int i = tid; i < 32 * KP; i += 256) {
      int d = i / KP, k = i - d * KP;
      Wp_t[(((size_t)p * 3 + mat) * ATT + d) * KP + k] = (k < HID) ? T[k * 34 + d] : (u16)0;
    }
  }
}

// ---------------- K1b: fold BN stats partials once -> mst_g[8][80][2] ----------------
__global__ __launch_bounds__(256) void k_fin(const float* __restrict__ part, float* __restrict__ mst_g) {
  int n = blockIdx.x;
  int t = threadIdx.x;
  if (t < 160) {
    int col = t >> 1, half = t & 1;
    float S = 0.f, Q = 0.f;
    #pragma unroll
    for (int i = 0; i < 16; i++) {
      int c = half * 16 + i;
      const float* p = part + ((size_t)(n * 32 + c) * IND + col) * 2;
      S += p[0]; Q += p[1];
    }
    S += __shfl_xor(S, 1);
    Q += __shfl_xor(Q, 1);
    if (half == 0) {
      float mean = S * (1.f / BATCH);
      float var = Q * (1.f / BATCH) - mean * mean;
      mst_g[(size_t)n * IND * 2 + col * 2] = mean;
      mst_g[(size_t)n * IND * 2 + col * 2 + 1] = rsqrtf(var + EPS);
    }
  }
}

// ---------------- K2: MFMA encoders + fused projections, LDS-bounced wide stores ----------------
// 64-row blocks, 4 waves. LDS: buf 17408 + outb 17408 + mst 640 + biases 1536 = 36992 B
// -> 4 blocks/CU (16 waves). All global stores: 16B coalesced, batched at barriers.
__global__ __launch_bounds__(256) void k_enc4(
    const void* __restrict__ s, const void* __restrict__ a,
    const u16* __restrict__ Wsa_t, const void* __restrict__ bsa,
    const u16* __restrict__ Wse_t, const void* __restrict__ bse,
    const u16* __restrict__ Wp_t, const void* __restrict__ bv_g,
    const float* __restrict__ mst_g, const int* __restrict__ flag,
    u16* __restrict__ SEo, u16* __restrict__ SELo, u16* __restrict__ KEYo, u16* __restrict__ VALo) {
  __shared__ __align__(16) u16 buf[64 * KP];    // sanb (stride KP3) -> KEY -> VAL -> SE
  __shared__ __align__(16) u16 outb[64 * KP];   // E -> SEL
  __shared__ float mst[IND * 2];
  __shared__ float bsaf[HID], bsef[HID], bvf[HID];
  bool bf = (*flag != 0);
  int tid = threadIdx.x;
  int n = blockIdx.y;
  int b0 = blockIdx.x * 64;
  int w = tid >> 6, lane = tid & 63, q = lane >> 4, rl = lane & 15;
  if (tid < HID) {
    bsaf[tid] = ldin(bsa, n * HID + tid, bf);
    bsef[tid] = ldin(bse, n * HID + tid, bf);
    bvf[tid]  = ldin(bv_g, tid, bf);
  }
  if (tid < IND * 2) mst[tid] = mst_g[(size_t)n * IND * 2 + tid];
  __syncthreads();   // B0: mst ready
  for (int i = tid; i < 64 * 32; i += 256) {          // s-part k 0..63
    int row = i >> 5, kp = i & 31;
    float x0, x1;
    if (bf) { u32 wv = ((const u32*)s)[((size_t)n * BATCH + b0 + row) * 32 + kp]; x0 = lo2f(wv); x1 = hi2f(wv); }
    else { const float* sf = (const float*)s + ((size_t)n * BATCH + b0 + row) * 64 + 2 * kp; x0 = sf[0]; x1 = sf[1]; }
    int k = 2 * kp;
    u32 o = (u32)f2bf((x0 - mst[k * 2]) * mst[k * 2 + 1]) |
            ((u32)f2bf((x1 - mst[k * 2 + 2]) * mst[k * 2 + 3]) << 16);
    *(u32*)&buf[row * KP3 + k] = o;
  }
  for (int i = tid; i < 64 * 8; i += 256) {           // a-part k 64..79
    int row = i >> 3, kp = i & 7;
    float x0, x1;
    if (bf) { u32 wv = ((const u32*)a)[((size_t)n * BATCH + b0 + row) * 8 + kp]; x0 = lo2f(wv); x1 = hi2f(wv); }
    else { const float* af = (const float*)a + ((size_t)n * BATCH + b0 + row) * 16 + 2 * kp; x0 = af[0]; x1 = af[1]; }
    int k = SD + 2 * kp;
    u32 o = (u32)f2bf((x0 - mst[k * 2]) * mst[k * 2 + 1]) |
            ((u32)f2bf((x1 - mst[k * 2 + 2]) * mst[k * 2 + 3]) << 16);
    *(u32*)&buf[row * KP3 + k] = o;
  }
  for (int i = tid; i < 64 * 12; i += 256) {          // zero pad k 80..103
    int row = i / 12, c2 = i - row * 12;
    *(u32*)&buf[row * KP3 + IND + 2 * c2] = 0u;
  }
  __syncthreads();   // B1: sanb staged
  const u16* WA = Wsa_t + (size_t)n * HID * KP3;
  const u16* WS = Wse_t + (size_t)n * HID * KPS;
  // E acc (K=96) and SE acc (K=64), both kept in regs
  float4f accE[8] = {};
  #pragma unroll
  for (int kc = 0; kc < 3; kc++) {
    short8 a0 = *(const short8*)&buf[(w * 16 + rl) * KP3 + kc * 32 + q * 8];
    #pragma unroll
    for (int nt = 0; nt < 8; nt++) {
      short8 bb = *(const short8*)(WA + (size_t)(nt * 16 + rl) * KP3 + kc * 32 + q * 8);
      accE[nt] = MFMA16(a0, bb, accE[nt]);
    }
  }
  float4f accS[8] = {};
  #pragma unroll
  for (int kc = 0; kc < 2; kc++) {
    short8 a0 = *(const short8*)&buf[(w * 16 + rl) * KP3 + kc * 32 + q * 8];
    #pragma unroll
    for (int nt = 0; nt < 8; nt++) {
      short8 bb = *(const short8*)(WS + (size_t)(nt * 16 + rl) * KPS + kc * 32 + q * 8);
      accS[nt] = MFMA16(a0, bb, accS[nt]);
    }
  }
  __syncthreads();   // B2: sanb reads done
  // outb <- E (wave-private rows); accE dies
  #pragma unroll
  for (int nt = 0; nt < 8; nt++)
    #pragma unroll
    for (int r = 0; r < 4; r++) {
      int row = w * 16 + q * 4 + r, col = nt * 16 + rl;
      outb[row * KP + col] = f2bf(lrelu(accE[nt][r] + bsaf[col]));
    }
  // hoist E A-frags (wave-private reads; reused by KEY and VAL passes)
  short8 afE[4];
  #pragma unroll
  for (int kc = 0; kc < 4; kc++)
    afE[kc] = lds_s8(&outb[(w * 16 + rl) * KP + kc * 32 + q * 8]);
  const size_t gb = ((size_t)n * BATCH + b0) * HID;
  // ---- KEY pass -> buf ----
  #pragma unroll
  for (int p = 0; p < HEADS; p++) {
    const u16* WK = Wp_t + (size_t)(p * 3 + 1) * ATT * KP;
    float4f ak[2] = {};
    #pragma unroll
    for (int kc = 0; kc < 4; kc++)
      #pragma unroll
      for (int nt = 0; nt < 2; nt++) {
        short8 bk = *(const short8*)(WK + (size_t)(nt * 16 + rl) * KP + kc * 32 + q * 8);
        ak[nt] = MFMA16(afE[kc], bk, ak[nt]);
      }
    #pragma unroll
    for (int nt = 0; nt < 2; nt++)
      #pragma unroll
      for (int r = 0; r < 4; r++) {
        int row = w * 16 + q * 4 + r;
        buf[row * KP + p * ATT + nt * 16 + rl] = f2bf(ak[nt][r]);
      }
  }
  __syncthreads();   // B3
  #pragma unroll
  for (int t = 0; t < 4; t++) {       // wide-store KEY (1KB contiguous per wave-inst)
    int idx = tid + t * 256;
    int row = idx >> 4, cc = idx & 15;
    *(short8*)(KEYo + gb + row * HID + cc * 8) = lds_s8(&buf[row * KP + cc * 8]);
  }
  __syncthreads();   // B4: KEY store reads done
  // ---- VAL pass -> buf (reads only afE regs + WV) ----
  #pragma unroll
  for (int p = 0; p < HEADS; p++) {
    const u16* WV = Wp_t + (size_t)(p * 3 + 2) * ATT * KP;
    float4f av[2] = {};
    #pragma unroll
    for (int kc = 0; kc < 4; kc++)
      #pragma unroll
      for (int nt = 0; nt < 2; nt++) {
        short8 bv8 = *(const short8*)(WV + (size_t)(nt * 16 + rl) * KP + kc * 32 + q * 8);
        av[nt] = MFMA16(afE[kc], bv8, av[nt]);
      }
    #pragma unroll
    for (int nt = 0; nt < 2; nt++)
      #pragma unroll
      for (int r = 0; r < 4; r++) {
        int row = w * 16 + q * 4 + r, d = nt * 16 + rl;
        buf[row * KP + p * ATT + d] = f2bf(lrelu(av[nt][r] + bvf[p * ATT + d]));
      }
  }
  __syncthreads();   // B5
  #pragma unroll
  for (int t = 0; t < 4; t++) {       // wide-store VAL
    int idx = tid + t * 256;
    int row = idx >> 4, cc = idx & 15;
    *(short8*)(VALo + gb + row * HID + cc * 8) = lds_s8(&buf[row * KP + cc * 8]);
  }
  __syncthreads();   // B6: VAL store reads done
  // ---- SE -> buf; SEL pass -> outb ----
  #pragma unroll
  for (int nt = 0; nt < 8; nt++)
    #pragma unroll
    for (int r = 0; r < 4; r++) {
      int row = w * 16 + q * 4 + r, col = nt * 16 + rl;
      buf[row * KP + col] = f2bf(lrelu(accS[nt][r] + bsef[col]));
    }
  short8 afS[4];
  #pragma unroll
  for (int kc = 0; kc < 4; kc++)
    afS[kc] = lds_s8(&buf[(w * 16 + rl) * KP + kc * 32 + q * 8]);
  #pragma unroll
  for (int p = 0; p < HEADS; p++) {
    const u16* WL = Wp_t + (size_t)(p * 3) * ATT * KP;
    float4f al[2] = {};
    #pragma unroll
    for (int kc = 0; kc < 4; kc++)
      #pragma unroll
      for (int nt = 0; nt < 2; nt++) {
        short8 bl = *(const short8*)(WL + (size_t)(nt * 16 + rl) * KP + kc * 32 + q * 8);
        al[nt] = MFMA16(afS[kc], bl, al[nt]);
      }
    #pragma unroll
    for (int nt = 0; nt < 2; nt++)
      #pragma unroll
      for (int r = 0; r < 4; r++) {
        int row = w * 16 + q * 4 + r;
        outb[row * KP + p * ATT + nt * 16 + rl] = f2bf(al[nt][r]);   // outb=E dead (afE cached)
      }
  }
  __syncthreads();   // B7
  #pragma unroll
  for (int t = 0; t < 4; t++) {       // wide-store SE + SEL
    int idx = tid + t * 256;
    int row = idx >> 4, cc = idx & 15;
    *(short8*)(SEo + gb + row * HID + cc * 8) = lds_s8(&buf[row * KP + cc * 8]);
    *(short8*)(SELo + gb + row * HID + cc * 8) = lds_s8(&outb[row * KP + cc * 8]);
  }
}

// ---------------- K3: pure attention — 1 barrier, barrier-free head loop ----------------
// LDS: valt 17408 + wb 3072 = 20480 B -> 7 blocks/CU (~28 waves: hides softmax chains).
__global__ __launch_bounds__(256) void k_attn(
    const u16* __restrict__ SEL, const u16* __restrict__ KEY, const u16* __restrict__ VAL,
    u16* __restrict__ OT) {
  __shared__ __align__(16) u16 valt[HEADS * ATT * VTS];   // [p*32+d][row'=b*8+j]
  __shared__ u16 wb[64 * WBS];                            // softmax weights, wave-private rows
  int tid = threadIdx.x;
  int b0 = blockIdx.x * 8;
  int w = tid >> 6, lane = tid & 63, q = lane >> 4, rl = lane & 15;
  // stage VAL -> valt (transposed for the PV B-operand)
  {
    const u32* vu = (const u32*)VAL;
    #pragma unroll
    for (int t = 0; t < 16; t++) {
      int idx = tid + t * 256;
      int rp = idx >> 6, c2 = idx & 63;   // rp = b*8 + agent
      u32 wv = vu[((size_t)(rp & 7) * BATCH + b0 + (rp >> 3)) * 64 + c2];
      int c = 2 * c2;
      valt[c * VTS + rp] = (u16)(wv & 0xffffu);
      valt[(c + 1) * VTS + rp] = (u16)(wv >> 16);
    }
  }
  __syncthreads();   // the only barrier
  const float scale = 0.17677669529663687f;
  // this lane's frag row': w*16+rl = b*8 + agent
  int j8 = rl & 7, bq = 2 * w + (rl >> 3);
  const size_t fbase = ((size_t)j8 * BATCH + b0 + bq) * HID;
  #pragma unroll
  for (int p = 0; p < HEADS; p++) {
    short8 sa = *(const short8*)(SEL + fbase + p * ATT + q * 8);
    short8 kb = *(const short8*)(KEY + fbase + p * ATT + q * 8);
    float4f zc = {};
    float4f c = MFMA16(sa, kb, zc);
    int nn = rl;
    #pragma unroll
    for (int r = 0; r < 4; r++) {
      int row = q * 4 + r;
      float x = c[r] * scale;
      if (row == nn) x = -1e9f;                    // self-mask (same b, i==j)
      float mx = x;
      mx = fmaxf(mx, __shfl_xor(mx, 1));
      mx = fmaxf(mx, __shfl_xor(mx, 2));
      mx = fmaxf(mx, __shfl_xor(mx, 4));
      float e = __expf(x - mx);
      float ssum = e;
      ssum += __shfl_xor(ssum, 1);
      ssum += __shfl_xor(ssum, 2);
      ssum += __shfl_xor(ssum, 4);
      float wv = e / ssum;
      if ((row >> 3) != (nn >> 3)) wv = 0.f;       // zero cross-b junk
      wb[(w * 16 + row) * WBS + nn] = f2bf(wv);    // wave-private rows
    }
    short8 aw;
    if (q < 2) aw = *(const short8*)&wb[(w * 16 + rl) * WBS + q * 8];
    else { short8 z = {}; aw = z; }
    float4f o[2] = {};
    #pragma unroll
    for (int nt = 0; nt < 2; nt++) {
      short8 bv8 = lds_s8(&valt[(p * ATT + nt * 16 + rl) * VTS + w * 16 + (q & 1) * 8]);
      o[nt] = MFMA16(aw, bv8, o[nt]);
    }
    #pragma unroll
    for (int nt = 0; nt < 2; nt++)
      #pragma unroll
      for (int r = 0; r < 4; r++) {
        int row = q * 4 + r;
        int b = 2 * w + (row >> 3), i = row & 7;
        OT[((size_t)i * BATCH + b0 + b) * HID + p * ATT + nt * 16 + rl] = f2bf(o[nt][r]);
      }
  }
}

// ---------------- K4: critic MFMA GEMM + argmax gather (byte-identical to round 6) ----------------
// LDS: Xt 34816 + wc2f 8192 + bc1f 512 + amax 512 = 44032 B
__global__ __launch_bounds__(256) void k_critic(
    const u16* __restrict__ SEi, const u16* __restrict__ OT, const void* __restrict__ a_g,
    const u16* __restrict__ Wc1t, const void* __restrict__ bc1_g,
    const void* __restrict__ Wc2_g, const void* __restrict__ bc2_g,
    const int* __restrict__ flag, void* __restrict__ qo) {
  __shared__ __align__(16) u16 Xt[128 * KP];   // input rows; reused as ht
  __shared__ float wc2f[HID * AD];
  __shared__ float bc1f[HID];
  __shared__ int amax[128];
  bool bf = (*flag != 0);
  int tid = threadIdx.x;
  int n = blockIdx.y;
  int b0 = blockIdx.x * 128;
  int w = tid >> 6, lane = tid & 63, q = lane >> 4, rl = lane & 15;
  if (tid < HID) bc1f[tid] = ldin(bc1_g, n * HID + tid, bf);
  const u16* WT = Wc1t + (size_t)n * HID * 256;

  float4f acc[2][8] = {};
  for (int ph = 0; ph < 2; ph++) {
    const u32* su = (const u32*)(ph == 0 ? SEi : OT);
    for (int idx = tid; idx < 128 * 64; idx += 256) {
      int row = idx >> 6, c = idx & 63;
      ((u32*)&Xt[row * KP])[c] = su[((size_t)n * BATCH + b0 + row) * 64 + c];
    }
    __syncthreads();
    #pragma unroll
    for (int kc = 0; kc < 4; kc++) {
      int ko = ph * HID + kc * 32;
      short8 a0 = *(const short8*)&Xt[((2 * w) * 16 + rl) * KP + kc * 32 + q * 8];
      short8 a1 = *(const short8*)&Xt[((2 * w + 1) * 16 + rl) * KP + kc * 32 + q * 8];
      #pragma unroll
      for (int nt = 0; nt < 8; nt++) {
        short8 bb = *(const short8*)(WT + (size_t)(nt * 16 + rl) * 256 + ko + q * 8);
        acc[0][nt] = MFMA16(a0, bb, acc[0][nt]);
        acc[1][nt] = MFMA16(a1, bb, acc[1][nt]);
      }
    }
    __syncthreads();
  }
  u16* ht = Xt;
  #pragma unroll
  for (int mi = 0; mi < 2; mi++)
    #pragma unroll
    for (int nt = 0; nt < 8; nt++)
      #pragma unroll
      for (int r = 0; r < 4; r++) {
        int row = (2 * w + mi) * 16 + q * 4 + r, col = nt * 16 + rl;
        ht[row * KP + col] = f2bf(lrelu(acc[mi][nt][r] + bc1f[col]));
      }
  for (int idx = tid; idx < HID * AD; idx += 256)
    wc2f[idx] = ldin(Wc2_g, (size_t)n * HID * AD + idx, bf);
  if (tid < 128) {
    size_t base = ((size_t)n * BATCH + b0 + tid) * AD;
    float best = ldin(a_g, base, bf); int bi = 0;
    for (int o = 1; o < AD; o++) {
      float v = ldin(a_g, base + o, bf);
      if (v > best) { best = v; bi = o; }   // strict > = first-max
    }
    amax[tid] = bi;
  }
  __syncthreads();
  {
    int b = tid >> 1, half = tid & 1;
    int col = amax[b];
    float acq = 0.f;
    const u16* hr = &ht[b * KP + half * 64];
    #pragma unroll
    for (int k = 0; k < 64; k++)
      acq = fmaf(bf2f(hr[k]), wc2f[(half * 64 + k) * AD + col], acq);
    acq += __shfl_xor(acq, 1);
    if (half == 0) {
      float v = acq + ldin(bc2_g, n * AD + col, bf);
      size_t oidx = (size_t)n * BATCH + b0 + b;
      if (bf) ((u16*)qo)[oidx] = f2bf(v);
      else    ((float*)qo)[oidx] = v;
    }
  }
}

extern "C" void kernel_launch(void* const* d_in, const int* in_sizes, int n_in,
                              void* d_out, int out_size, void* d_ws, size_t ws_size,
                              hipStream_t stream) {
  const void* s   = d_in[0];
  const void* a   = d_in[1];
  const void* Wsa = d_in[2];
  const void* bsa = d_in[3];
  const void* Wse = d_in[4];
  const void* bse = d_in[5];
  const void* Wk  = d_in[6];
  const void* Wsl = d_in[7];
  const void* Wv  = d_in[8];
  const void* bv  = d_in[9];
  const void* Wc1 = d_in[10];
  const void* bc1 = d_in[11];
  const void* Wc2 = d_in[12];
  const void* bc2 = d_in[13];

  char* ws = (char*)d_ws;
  int*   flag  = (int*)ws;
  float* part  = (float*)(ws + 256);
  float* mst_g = (float*)(ws + 164096);
  u16*   Wsa_t = (u16*)(ws + 169216);
  u16*   Wse_t = (u16*)(ws + 382208);
  u16*   Wp_t  = (u16*)(ws + 529664);
  u16*   Wc1t  = (u16*)(ws + 634112);
  u16*   SEb   = (u16*)(ws + 1158400);
  u16*   SEL   = (u16*)(ws + 1158400 + 1ull * 33554432ull);
  u16*   KEY   = (u16*)(ws + 1158400 + 2ull * 33554432ull);
  u16*   VAL   = (u16*)(ws + 1158400 + 3ull * 33554432ull);
  u16*   OT    = (u16*)(ws + 1158400 + 4ull * 33554432ull);

  k_prep<<<316, 256, 0, stream>>>(s, a, Wsa, Wse, Wsl, Wk, Wv, Wc1,
                                  flag, part, Wsa_t, Wse_t, Wp_t, Wc1t);
  k_fin<<<NA, 256, 0, stream>>>(part, mst_g);
  k_enc4<<<dim3(BATCH / 64, NA), 256, 0, stream>>>(s, a, Wsa_t, bsa, Wse_t, bse, Wp_t, bv,
                                                   mst_g, flag, SEb, SEL, KEY, VAL);
  k_attn<<<BATCH / 8, 256, 0, stream>>>(SEL, KEY, VAL, OT);
  k_critic<<<dim3(BATCH / 128, NA), 256, 0, stream>>>(SEb, OT, a, Wc1t, bc1, Wc2, bc2, flag, d_out);
}

// Round 3
// 283.405 us; speedup vs baseline: 1.0609x; 1.0609x over previous
//
#include <hip/hip_runtime.h>

// Attention_Critic on MI355X — round 12: N-split projection GEMMs in enc.
//  - Theory: enc3/enc4 (~100us) were L1/L2 B-operand-feed bound: every wave read
//    the full B of every GEMM (600KB/block). enc5 N-splits the 3 projection
//    GEMMs (wave w owns 32 output cols, A-frags from LDS) -> B read once per
//    block (~260KB). Two extra barriers (E/SE tiles cross-wave visible).
//  - k_prep: proj weights now stored as 3 contiguous [128 col][KP] matrices.
//  - k_attn: output written IN-PLACE into SEL (read-before-write per head slice,
//    wave-private batch pairs; pointer deliberately NOT __restrict__) -> OT array
//    dropped, ws 161->135MB.
//  - k_critic: byte-identical (reads SEL region as OT).
//
// ws layout (bytes):
//   [0,256)        int flag (1 = bf16 inputs, 0 = f32)
//   [256,+163840)  stats partials f32 [8][32][80][2]
//   [164096,+5120) mst_g f32 [8][80][2]  (mean, rstd)
//   [169216,...)   Wsa_t bf16 [8][128 col][104 k]
//   [382208,...)   Wse_t bf16 [8][128 col][72 k]
//   [529664,...)   Wp_t  bf16 [3 mat][128 col][136 k]  (mat 0=sel,1=key,2=val; col=p*32+d)
//   [634112,...)   Wc1t  bf16 [8][128 col][256 k]
//   [1158400,+32M) SE  bf16 [8][16384][128]
//   [+32M,+64M)    SEL bf16 [8][16384][128]  (attn output overwrites in place)
//   [+64M,+96M)    KEY bf16 [8][16384][128]
//   [+96M,+128M)   VAL bf16 [8][16384][128]

typedef unsigned short u16;
typedef unsigned int u32;

#define NA 8
#define BATCH 16384
#define SD 64
#define AD 16
#define IND 80
#define HID 128
#define HEADS 4
#define ATT 32
#define EPS 1e-5f
#define KP 136    // u16 stride, 128-k tiles
#define KP3 104   // u16 stride, 96-k tiles (Wsa_t)
#define KPS 72    // u16 stride, 64-k tiles (Wse_t)
#define VTS 68    // u16 stride, valt [32 d][64 row']
#define WBS 24    // u16 stride, softmax weight tiles

using short8 = __attribute__((ext_vector_type(8))) short;
using float4f = __attribute__((ext_vector_type(4))) float;
#define MFMA16(a, b, c) __builtin_amdgcn_mfma_f32_16x16x32_bf16((a), (b), (c), 0, 0, 0)

__device__ __forceinline__ float bf2f(u16 u) { union { u32 i; float f; } v; v.i = ((u32)u) << 16; return v.f; }
__device__ __forceinline__ float lo2f(u32 w) { union { u32 i; float f; } v; v.i = w << 16; return v.f; }
__device__ __forceinline__ float hi2f(u32 w) { union { u32 i; float f; } v; v.i = w & 0xffff0000u; return v.f; }
__device__ __forceinline__ u16 f2bf(float f) {
  union { float f; u32 i; } v; v.f = f;
  u32 x = v.i;
  x += 0x7fffu + ((x >> 16) & 1u);   // RNE
  return (u16)(x >> 16);
}
__device__ __forceinline__ float lrelu(float x) { return x > 0.f ? x : 0.01f * x; }
__device__ __forceinline__ float ldin(const void* p, size_t i, bool bf) {
  return bf ? bf2f(((const u16*)p)[i]) : ((const float*)p)[i];
}
__device__ __forceinline__ u16 ldbf(const void* p, size_t i, bool bf) {
  return bf ? ((const u16*)p)[i] : f2bf(((const float*)p)[i]);
}
__device__ __forceinline__ short8 lds_s8(const u16* p) {   // 16B LDS load, 4B-aligned ok
  union { short8 v; u32 u[4]; } t;
  const u32* q = (const u32*)p;
  t.u[0] = q[0]; t.u[1] = q[1]; t.u[2] = q[2]; t.u[3] = q[3];
  return t.v;
}

// ---------------- K1: merged BN stats + weight prep (per-block dtype detect) ----------------
// blocks [0,256): stats; [256,288): Wc1; [288,296): Wsa; [296,304): Wse; [304,316): Wp.
__global__ __launch_bounds__(256) void k_prep(
    const void* __restrict__ s, const void* __restrict__ a,
    const void* __restrict__ Wsa, const void* __restrict__ Wse,
    const void* __restrict__ Wsl, const void* __restrict__ Wk, const void* __restrict__ Wv,
    const void* __restrict__ Wc1,
    int* __restrict__ flag, float* __restrict__ part,
    u16* __restrict__ Wsa_t, u16* __restrict__ Wse_t, u16* __restrict__ Wp_t, u16* __restrict__ Wc1t) {
  __shared__ u16 T[80 * 130];
  __shared__ float S0[256], Q0[256], S1[256], Q1[256];
  __shared__ int cnt[2];
  int tid = threadIdx.x;
  if (tid < 2) cnt[tid] = 0;
  __syncthreads();
  {   // local dtype detection (all blocks)
    u32 wv = ((const u32*)s)[tid];
    u32 lo = wv & 0xffffu, e = (lo >> 7) & 0xffu;
    if (lo == 0u || lo == 0x8000u) atomicAdd(&cnt[1], 1);
    else if (e < 0x70u || e > 0x8fu) atomicAdd(&cnt[0], 1);
  }
  __syncthreads();
  bool bf = !(cnt[0] >= 64 || cnt[1] >= 192);
  if (blockIdx.x == 0 && tid == 0) *flag = bf ? 1 : 0;
  int blkr = blockIdx.x;
  if (blkr < 256) {   // ---- stats ----
    int blk = blkr, n = blk >> 5, c = blk & 31, b0 = c << 9;
    {
      int f2 = tid & 31, rg = tid >> 5;
      float s0 = 0.f, s1 = 0.f, q0 = 0.f, q1 = 0.f;
      for (int i = 0; i < 64; i++) {
        int b = b0 + rg + 8 * i;
        float x0, x1;
        if (bf) { u32 wv = ((const u32*)s)[((size_t)n * BATCH + b) * 32 + f2]; x0 = lo2f(wv); x1 = hi2f(wv); }
        else { const float* sf = (const float*)s + ((size_t)n * BATCH + b) * 64 + 2 * f2; x0 = sf[0]; x1 = sf[1]; }
        s0 += x0; q0 += x0 * x0; s1 += x1; q1 += x1 * x1;
      }
      S0[tid] = s0; Q0[tid] = q0; S1[tid] = s1; Q1[tid] = q1;
    }
    __syncthreads();
    if (tid < 64) {
      int f2 = tid >> 1, odd = tid & 1;
      float S = 0.f, Q = 0.f;
      for (int rg = 0; rg < 8; rg++) {
        int ix = rg * 32 + f2;
        S += odd ? S1[ix] : S0[ix];
        Q += odd ? Q1[ix] : Q0[ix];
      }
      float* p = part + ((size_t)blk * IND + tid) * 2;
      p[0] = S; p[1] = Q;
    }
    __syncthreads();
    {
      int f2 = tid & 7, rg = tid >> 3;
      float s0 = 0.f, s1 = 0.f, q0 = 0.f, q1 = 0.f;
      for (int i = 0; i < 16; i++) {
        int b = b0 + rg + 32 * i;
        float x0, x1;
        if (bf) { u32 wv = ((const u32*)a)[((size_t)n * BATCH + b) * 8 + f2]; x0 = lo2f(wv); x1 = hi2f(wv); }
        else { const float* af = (const float*)a + ((size_t)n * BATCH + b) * 16 + 2 * f2; x0 = af[0]; x1 = af[1]; }
        s0 += x0; q0 += x0 * x0; s1 += x1; q1 += x1 * x1;
      }
      S0[tid] = s0; Q0[tid] = q0; S1[tid] = s1; Q1[tid] = q1;
    }
    __syncthreads();
    if (tid < 16) {
      int f2 = tid >> 1, odd = tid & 1;
      float S = 0.f, Q = 0.f;
      for (int rg = 0; rg < 32; rg++) {
        int ix = rg * 8 + f2;
        S += odd ? S1[ix] : S0[ix];
        Q += odd ? Q1[ix] : Q0[ix];
      }
      float* p = part + ((size_t)blk * IND + SD + tid) * 2;
      p[0] = S; p[1] = Q;
    }
    return;
  }
  int blk = blkr - 256;   // ---- weight prep ----
  if (blk < 32) {                       // Wc1 [n][256][128] -> Wc1t [n][128][256]
    int n = blk >> 2, k0 = (blk & 3) * 64;
    for (int i = tid; i < 64 * 128; i += 256) {
      int kr = i >> 7, cc = i & 127;
      T[kr * 130 + cc] = ldbf(Wc1, ((size_t)n * 256 + k0 + kr) * 128 + cc, bf);
    }
    __syncthreads();
    for (int i = tid; i < 128 * 64; i += 256) {
      int col = i >> 6, kk = i & 63;
      Wc1t[((size_t)n * 128 + col) * 256 + k0 + kk] = T[kk * 130 + col];
    }
  } else if (blk < 40) {                // Wsa -> Wsa_t
    int n = blk - 32;
    for (int i = tid; i < 80 * 128; i += 256) {
      int kr = i >> 7, cc = i & 127;
      T[kr * 130 + cc] = ldbf(Wsa, ((size_t)n * IND + kr) * 128 + cc, bf);
    }
    __syncthreads();
    for (int i = tid; i < 128 * KP3; i += 256) {
      int col = i / KP3, k = i - col * KP3;
      Wsa_t[((size_t)n * 128 + col) * KP3 + k] = (k < IND) ? T[k * 130 + col] : (u16)0;
    }
  } else if (blk < 48) {                // Wse -> Wse_t
    int n = blk - 40;
    for (int i = tid; i < 64 * 128; i += 256) {
      int kr = i >> 7, cc = i & 127;
      T[kr * 130 + cc] = ldbf(Wse, ((size_t)n * SD + kr) * 128 + cc, bf);
    }
    __syncthreads();
    for (int i = tid; i < 128 * KPS; i += 256) {
      int col = i / KPS, k = i - col * KPS;
      Wse_t[((size_t)n * 128 + col) * KPS + k] = (k < SD) ? T[k * 130 + col] : (u16)0;
    }
  } else {                              // Wp -> Wp_t [mat][col=p*32+d][KP]
    int pm = blk - 48, p = pm / 3, mat = pm - 3 * p;
    const void* W = (mat == 0) ? Wsl : (mat == 1) ? Wk : Wv;
    for (int i = tid; i < 128 * 32; i += 256) {
      int kr = i >> 5, d = i & 31;
      T[kr * 34 + d] = ldbf(W, ((size_t)p * HID + kr) * ATT + d, bf);
    }
    __syncthreads();
    for (int i = tid; i < 32 * KP; i += 256) {
      int d = i / KP, k = i - d * KP;
      Wp_t[((size_t)mat * HID + p * ATT + d) * KP + k] = (k < HID) ? T[k * 34 + d] : (u16)0;
    }
  }
}

// ---------------- K1b: fold BN stats partials once -> mst_g[8][80][2] ----------------
__global__ __launch_bounds__(256) void k_fin(const float* __restrict__ part, float* __restrict__ mst_g) {
  int n = blockIdx.x;
  int t = threadIdx.x;
  if (t < 160) {
    int col = t >> 1, half = t & 1;
    float S = 0.f, Q = 0.f;
    #pragma unroll
    for (int i = 0; i < 16; i++) {
      int c = half * 16 + i;
      const float* p = part + ((size_t)(n * 32 + c) * IND + col) * 2;
      S += p[0]; Q += p[1];
    }
    S += __shfl_xor(S, 1);
    Q += __shfl_xor(Q, 1);
    if (half == 0) {
      float mean = S * (1.f / BATCH);
      float var = Q * (1.f / BATCH) - mean * mean;
      mst_g[(size_t)n * IND * 2 + col * 2] = mean;
      mst_g[(size_t)n * IND * 2 + col * 2 + 1] = rsqrtf(var + EPS);
    }
  }
}

// ---------------- K2: encoders + N-split fused projections ----------------
// 64-row blocks, 4 waves. LDS: buf 17408 + outb 17408 + mst 640 + biases 1536 = 36992 B
// -> 4 blocks/CU. Proj GEMMs N-split: wave w computes cols [32w,32w+32) for ALL rows;
// B operands read ONCE per block (vs 4x), A-frags from LDS.
__global__ __launch_bounds__(256) void k_enc5(
    const void* __restrict__ s, const void* __restrict__ a,
    const u16* __restrict__ Wsa_t, const void* __restrict__ bsa,
    const u16* __restrict__ Wse_t, const void* __restrict__ bse,
    const u16* __restrict__ Wp_t, const void* __restrict__ bv_g,
    const float* __restrict__ mst_g, const int* __restrict__ flag,
    u16* __restrict__ SEo, u16* __restrict__ SELo, u16* __restrict__ KEYo, u16* __restrict__ VALo) {
  __shared__ __align__(16) u16 buf[64 * KP];    // sanb (stride KP3) -> KEY -> VAL -> SEL
  __shared__ __align__(16) u16 outb[64 * KP];   // E -> SE
  __shared__ float mst[IND * 2];
  __shared__ float bsaf[HID], bsef[HID], bvf[HID];
  bool bf = (*flag != 0);
  int tid = threadIdx.x;
  int n = blockIdx.y;
  int b0 = blockIdx.x * 64;
  int w = tid >> 6, lane = tid & 63, q = lane >> 4, rl = lane & 15;
  if (tid < HID) {
    bsaf[tid] = ldin(bsa, n * HID + tid, bf);
    bsef[tid] = ldin(bse, n * HID + tid, bf);
    bvf[tid]  = ldin(bv_g, tid, bf);
  }
  if (tid < IND * 2) mst[tid] = mst_g[(size_t)n * IND * 2 + tid];
  __syncthreads();   // B0: mst ready
  for (int i = tid; i < 64 * 32; i += 256) {          // s-part k 0..63
    int row = i >> 5, kp = i & 31;
    float x0, x1;
    if (bf) { u32 wv = ((const u32*)s)[((size_t)n * BATCH + b0 + row) * 32 + kp]; x0 = lo2f(wv); x1 = hi2f(wv); }
    else { const float* sf = (const float*)s + ((size_t)n * BATCH + b0 + row) * 64 + 2 * kp; x0 = sf[0]; x1 = sf[1]; }
    int k = 2 * kp;
    u32 o = (u32)f2bf((x0 - mst[k * 2]) * mst[k * 2 + 1]) |
            ((u32)f2bf((x1 - mst[k * 2 + 2]) * mst[k * 2 + 3]) << 16);
    *(u32*)&buf[row * KP3 + k] = o;
  }
  for (int i = tid; i < 64 * 8; i += 256) {           // a-part k 64..79
    int row = i >> 3, kp = i & 7;
    float x0, x1;
    if (bf) { u32 wv = ((const u32*)a)[((size_t)n * BATCH + b0 + row) * 8 + kp]; x0 = lo2f(wv); x1 = hi2f(wv); }
    else { const float* af = (const float*)a + ((size_t)n * BATCH + b0 + row) * 16 + 2 * kp; x0 = af[0]; x1 = af[1]; }
    int k = SD + 2 * kp;
    u32 o = (u32)f2bf((x0 - mst[k * 2]) * mst[k * 2 + 1]) |
            ((u32)f2bf((x1 - mst[k * 2 + 2]) * mst[k * 2 + 3]) << 16);
    *(u32*)&buf[row * KP3 + k] = o;
  }
  for (int i = tid; i < 64 * 12; i += 256) {          // zero pad k 80..103
    int row = i / 12, c2 = i - row * 12;
    *(u32*)&buf[row * KP3 + IND + 2 * c2] = 0u;
  }
  __syncthreads();   // B1: sanb staged
  const u16* WA = Wsa_t + (size_t)n * HID * KP3;
  const u16* WS = Wse_t + (size_t)n * HID * KPS;
  // E acc (K=96) and SE acc (K=64), M-split (wave w owns rows 16w..16w+15)
  float4f accE[8] = {};
  #pragma unroll
  for (int kc = 0; kc < 3; kc++) {
    short8 a0 = *(const short8*)&buf[(w * 16 + rl) * KP3 + kc * 32 + q * 8];
    #pragma unroll
    for (int nt = 0; nt < 8; nt++) {
      short8 bb = *(const short8*)(WA + (size_t)(nt * 16 + rl) * KP3 + kc * 32 + q * 8);
      accE[nt] = MFMA16(a0, bb, accE[nt]);
    }
  }
  float4f accS[8] = {};
  #pragma unroll
  for (int kc = 0; kc < 2; kc++) {
    short8 a0 = *(const short8*)&buf[(w * 16 + rl) * KP3 + kc * 32 + q * 8];
    #pragma unroll
    for (int nt = 0; nt < 8; nt++) {
      short8 bb = *(const short8*)(WS + (size_t)(nt * 16 + rl) * KPS + kc * 32 + q * 8);
      accS[nt] = MFMA16(a0, bb, accS[nt]);
    }
  }
  __syncthreads();   // B2: sanb reads done
  // outb <- E (wave-private rows); accE dies
  #pragma unroll
  for (int nt = 0; nt < 8; nt++)
    #pragma unroll
    for (int r = 0; r < 4; r++) {
      int row = w * 16 + q * 4 + r, col = nt * 16 + rl;
      outb[row * KP + col] = f2bf(lrelu(accE[nt][r] + bsaf[col]));
    }
  __syncthreads();   // B2b: E tile fully visible (proj A-frags read ALL rows)
  const size_t gb = ((size_t)n * BATCH + b0) * HID;
  const u16* WSL = Wp_t;                               // mat 0, [128][KP]
  const u16* WKm = Wp_t + (size_t)HID * KP;            // mat 1
  const u16* WVm = Wp_t + (size_t)2 * HID * KP;        // mat 2
  // ---- KEY pass (N-split) -> buf ----
  {
    float4f ack[4][2] = {};
    #pragma unroll
    for (int kc = 0; kc < 4; kc++) {
      short8 af[4];
      #pragma unroll
      for (int mt = 0; mt < 4; mt++)
        af[mt] = lds_s8(&outb[(mt * 16 + rl) * KP + kc * 32 + q * 8]);
      #pragma unroll
      for (int nt = 0; nt < 2; nt++) {
        short8 bk = *(const short8*)(WKm + (size_t)(w * 32 + nt * 16 + rl) * KP + kc * 32 + q * 8);
        #pragma unroll
        for (int mt = 0; mt < 4; mt++)
          ack[mt][nt] = MFMA16(af[mt], bk, ack[mt][nt]);
      }
    }
    #pragma unroll
    for (int mt = 0; mt < 4; mt++)
      #pragma unroll
      for (int nt = 0; nt < 2; nt++)
        #pragma unroll
        for (int r = 0; r < 4; r++) {
          int row = mt * 16 + q * 4 + r, col = w * 32 + nt * 16 + rl;
          buf[row * KP + col] = f2bf(ack[mt][nt][r]);
        }
  }
  __syncthreads();   // B3: KEY tile visible
  #pragma unroll
  for (int t = 0; t < 4; t++) {       // wide-store KEY (1KB contiguous per wave-inst)
    int idx = tid + t * 256;
    int row = idx >> 4, cc = idx & 15;
    *(short8*)(KEYo + gb + row * HID + cc * 8) = lds_s8(&buf[row * KP + cc * 8]);
  }
  __syncthreads();   // B4: KEY store LDS-reads done
  // ---- VAL pass (N-split, reads E from outb) -> buf ----
  {
    float4f av[4][2] = {};
    #pragma unroll
    for (int kc = 0; kc < 4; kc++) {
      short8 af[4];
      #pragma unroll
      for (int mt = 0; mt < 4; mt++)
        af[mt] = lds_s8(&outb[(mt * 16 + rl) * KP + kc * 32 + q * 8]);
      #pragma unroll
      for (int nt = 0; nt < 2; nt++) {
        short8 bv8 = *(const short8*)(WVm + (size_t)(w * 32 + nt * 16 + rl) * KP + kc * 32 + q * 8);
        #pragma unroll
        for (int mt = 0; mt < 4; mt++)
          av[mt][nt] = MFMA16(af[mt], bv8, av[mt][nt]);
      }
    }
    #pragma unroll
    for (int mt = 0; mt < 4; mt++)
      #pragma unroll
      for (int nt = 0; nt < 2; nt++)
        #pragma unroll
        for (int r = 0; r < 4; r++) {
          int row = mt * 16 + q * 4 + r, col = w * 32 + nt * 16 + rl;
          buf[row * KP + col] = f2bf(lrelu(av[mt][nt][r] + bvf[col]));
        }
  }
  __syncthreads();   // B5: VAL tile visible + all E reads done (outb free)
  #pragma unroll
  for (int t = 0; t < 4; t++) {       // wide-store VAL
    int idx = tid + t * 256;
    int row = idx >> 4, cc = idx & 15;
    *(short8*)(VALo + gb + row * HID + cc * 8) = lds_s8(&buf[row * KP + cc * 8]);
  }
  // outb <- SE (wave-private rows); accS dies
  #pragma unroll
  for (int nt = 0; nt < 8; nt++)
    #pragma unroll
    for (int r = 0; r < 4; r++) {
      int row = w * 16 + q * 4 + r, col = nt * 16 + rl;
      outb[row * KP + col] = f2bf(lrelu(accS[nt][r] + bsef[col]));
    }
  __syncthreads();   // B6: SE visible + VAL store LDS-reads done
  // ---- SEL pass (N-split, reads SE from outb) -> buf ----
  {
    float4f al[4][2] = {};
    #pragma unroll
    for (int kc = 0; kc < 4; kc++) {
      short8 af[4];
      #pragma unroll
      for (int mt = 0; mt < 4; mt++)
        af[mt] = lds_s8(&outb[(mt * 16 + rl) * KP + kc * 32 + q * 8]);
      #pragma unroll
      for (int nt = 0; nt < 2; nt++) {
        short8 bl = *(const short8*)(WSL + (size_t)(w * 32 + nt * 16 + rl) * KP + kc * 32 + q * 8);
        #pragma unroll
        for (int mt = 0; mt < 4; mt++)
          al[mt][nt] = MFMA16(af[mt], bl, al[mt][nt]);
      }
    }
    #pragma unroll
    for (int mt = 0; mt < 4; mt++)
      #pragma unroll
      for (int nt = 0; nt < 2; nt++)
        #pragma unroll
        for (int r = 0; r < 4; r++) {
          int row = mt * 16 + q * 4 + r, col = w * 32 + nt * 16 + rl;
          buf[row * KP + col] = f2bf(al[mt][nt][r]);
        }
  }
  __syncthreads();   // B7: SEL tile visible
  #pragma unroll
  for (int t = 0; t < 4; t++) {       // wide-store SEL + SE
    int idx = tid + t * 256;
    int row = idx >> 4, cc = idx & 15;
    *(short8*)(SELo + gb + row * HID + cc * 8) = lds_s8(&buf[row * KP + cc * 8]);
    *(short8*)(SEo + gb + row * HID + cc * 8) = lds_s8(&outb[row * KP + cc * 8]);
  }
}

// ---------------- K3: attention, output in-place into SEL ----------------
// LDS: valt 17408 + wb 3072 = 20480 B -> 7 blocks/CU (~28 waves).
// SELO deliberately NOT __restrict__: reads of head p precede writes of head p
// (same slice); compiler must preserve order across heads.
__global__ __launch_bounds__(256) void k_attn(
    u16* SELO, const u16* __restrict__ KEY, const u16* __restrict__ VAL) {
  __shared__ __align__(16) u16 valt[HEADS * ATT * VTS];   // [p*32+d][row'=b*8+j]
  __shared__ u16 wb[64 * WBS];                            // softmax weights, wave-private rows
  int tid = threadIdx.x;
  int b0 = blockIdx.x * 8;
  int w = tid >> 6, lane = tid & 63, q = lane >> 4, rl = lane & 15;
  // stage VAL -> valt (transposed for the PV B-operand)
  {
    const u32* vu = (const u32*)VAL;
    #pragma unroll
    for (int t = 0; t < 16; t++) {
      int idx = tid + t * 256;
      int rp = idx >> 6, c2 = idx & 63;   // rp = b*8 + agent
      u32 wv = vu[((size_t)(rp & 7) * BATCH + b0 + (rp >> 3)) * 64 + c2];
      int c = 2 * c2;
      valt[c * VTS + rp] = (u16)(wv & 0xffffu);
      valt[(c + 1) * VTS + rp] = (u16)(wv >> 16);
    }
  }
  __syncthreads();   // the only barrier
  const float scale = 0.17677669529663687f;
  // this lane's frag row': w*16+rl = b*8 + agent
  int j8 = rl & 7, bq = 2 * w + (rl >> 3);
  const size_t fbase = ((size_t)j8 * BATCH + b0 + bq) * HID;
  #pragma unroll
  for (int p = 0; p < HEADS; p++) {
    short8 sa = *(const short8*)(SELO + fbase + p * ATT + q * 8);
    short8 kb = *(const short8*)(KEY + fbase + p * ATT + q * 8);
    float4f zc = {};
    float4f c = MFMA16(sa, kb, zc);
    int nn = rl;
    #pragma unroll
    for (int r = 0; r < 4; r++) {
      int row = q * 4 + r;
      float x = c[r] * scale;
      if (row == nn) x = -1e9f;                    // self-mask (same b, i==j)
      float mx = x;
      mx = fmaxf(mx, __shfl_xor(mx, 1));
      mx = fmaxf(mx, __shfl_xor(mx, 2));
      mx = fmaxf(mx, __shfl_xor(mx, 4));
      float e = __expf(x - mx);
      float ssum = e;
      ssum += __shfl_xor(ssum, 1);
      ssum += __shfl_xor(ssum, 2);
      ssum += __shfl_xor(ssum, 4);
      float wv = e / ssum;
      if ((row >> 3) != (nn >> 3)) wv = 0.f;       // zero cross-b junk
      wb[(w * 16 + row) * WBS + nn] = f2bf(wv);    // wave-private rows
    }
    short8 aw;
    if (q < 2) aw = *(const short8*)&wb[(w * 16 + rl) * WBS + q * 8];
    else { short8 z = {}; aw = z; }
    float4f o[2] = {};
    #pragma unroll
    for (int nt = 0; nt < 2; nt++) {
      short8 bv8 = lds_s8(&valt[(p * ATT + nt * 16 + rl) * VTS + w * 16 + (q & 1) * 8]);
      o[nt] = MFMA16(aw, bv8, o[nt]);
    }
    #pragma unroll
    for (int nt = 0; nt < 2; nt++)
      #pragma unroll
      for (int r = 0; r < 4; r++) {
        int row = q * 4 + r;
        int b = 2 * w + (row >> 3), i = row & 7;
        SELO[((size_t)i * BATCH + b0 + b) * HID + p * ATT + nt * 16 + rl] = f2bf(o[nt][r]);
      }
  }
}

// ---------------- K4: critic MFMA GEMM + argmax gather (byte-identical to round 6) ----------------
// LDS: Xt 34816 + wc2f 8192 + bc1f 512 + amax 512 = 44032 B
__global__ __launch_bounds__(256) void k_critic(
    const u16* __restrict__ SEi, const u16* __restrict__ OT, const void* __restrict__ a_g,
    const u16* __restrict__ Wc1t, const void* __restrict__ bc1_g,
    const void* __restrict__ Wc2_g, const void* __restrict__ bc2_g,
    const int* __restrict__ flag, void* __restrict__ qo) {
  __shared__ __align__(16) u16 Xt[128 * KP];   // input rows; reused as ht
  __shared__ float wc2f[HID * AD];
  __shared__ float bc1f[HID];
  __shared__ int amax[128];
  bool bf = (*flag != 0);
  int tid = threadIdx.x;
  int n = blockIdx.y;
  int b0 = blockIdx.x * 128;
  int w = tid >> 6, lane = tid & 63, q = lane >> 4, rl = lane & 15;
  if (tid < HID) bc1f[tid] = ldin(bc1_g, n * HID + tid, bf);
  const u16* WT = Wc1t + (size_t)n * HID * 256;

  float4f acc[2][8] = {};
  for (int ph = 0; ph < 2; ph++) {
    const u32* su = (const u32*)(ph == 0 ? SEi : OT);
    for (int idx = tid; idx < 128 * 64; idx += 256) {
      int row = idx >> 6, c = idx & 63;
      ((u32*)&Xt[row * KP])[c] = su[((size_t)n * BATCH + b0 + row) * 64 + c];
    }
    __syncthreads();
    #pragma unroll
    for (int kc = 0; kc < 4; kc++) {
      int ko = ph * HID + kc * 32;
      short8 a0 = *(const short8*)&Xt[((2 * w) * 16 + rl) * KP + kc * 32 + q * 8];
      short8 a1 = *(const short8*)&Xt[((2 * w + 1) * 16 + rl) * KP + kc * 32 + q * 8];
      #pragma unroll
      for (int nt = 0; nt < 8; nt++) {
        short8 bb = *(const short8*)(WT + (size_t)(nt * 16 + rl) * 256 + ko + q * 8);
        acc[0][nt] = MFMA16(a0, bb, acc[0][nt]);
        acc[1][nt] = MFMA16(a1, bb, acc[1][nt]);
      }
    }
    __syncthreads();
  }
  u16* ht = Xt;
  #pragma unroll
  for (int mi = 0; mi < 2; mi++)
    #pragma unroll
    for (int nt = 0; nt < 8; nt++)
      #pragma unroll
      for (int r = 0; r < 4; r++) {
        int row = (2 * w + mi) * 16 + q * 4 + r, col = nt * 16 + rl;
        ht[row * KP + col] = f2bf(lrelu(acc[mi][nt][r] + bc1f[col]));
      }
  for (int idx = tid; idx < HID * AD; idx += 256)
    wc2f[idx] = ldin(Wc2_g, (size_t)n * HID * AD + idx, bf);
  if (tid < 128) {
    size_t base = ((size_t)n * BATCH + b0 + tid) * AD;
    float best = ldin(a_g, base, bf); int bi = 0;
    for (int o = 1; o < AD; o++) {
      float v = ldin(a_g, base + o, bf);
      if (v > best) { best = v; bi = o; }   // strict > = first-max
    }
    amax[tid] = bi;
  }
  __syncthreads();
  {
    int b = tid >> 1, half = tid & 1;
    int col = amax[b];
    float acq = 0.f;
    const u16* hr = &ht[b * KP + half * 64];
    #pragma unroll
    for (int k = 0; k < 64; k++)
      acq = fmaf(bf2f(hr[k]), wc2f[(half * 64 + k) * AD + col], acq);
    acq += __shfl_xor(acq, 1);
    if (half == 0) {
      float v = acq + ldin(bc2_g, n * AD + col, bf);
      size_t oidx = (size_t)n * BATCH + b0 + b;
      if (bf) ((u16*)qo)[oidx] = f2bf(v);
      else    ((float*)qo)[oidx] = v;
    }
  }
}

extern "C" void kernel_launch(void* const* d_in, const int* in_sizes, int n_in,
                              void* d_out, int out_size, void* d_ws, size_t ws_size,
                              hipStream_t stream) {
  const void* s   = d_in[0];
  const void* a   = d_in[1];
  const void* Wsa = d_in[2];
  const void* bsa = d_in[3];
  const void* Wse = d_in[4];
  const void* bse = d_in[5];
  const void* Wk  = d_in[6];
  const void* Wsl = d_in[7];
  const void* Wv  = d_in[8];
  const void* bv  = d_in[9];
  const void* Wc1 = d_in[10];
  const void* bc1 = d_in[11];
  const void* Wc2 = d_in[12];
  const void* bc2 = d_in[13];

  char* ws = (char*)d_ws;
  int*   flag  = (int*)ws;
  float* part  = (float*)(ws + 256);
  float* mst_g = (float*)(ws + 164096);
  u16*   Wsa_t = (u16*)(ws + 169216);
  u16*   Wse_t = (u16*)(ws + 382208);
  u16*   Wp_t  = (u16*)(ws + 529664);
  u16*   Wc1t  = (u16*)(ws + 634112);
  u16*   SEb   = (u16*)(ws + 1158400);
  u16*   SEL   = (u16*)(ws + 1158400 + 1ull * 33554432ull);
  u16*   KEY   = (u16*)(ws + 1158400 + 2ull * 33554432ull);
  u16*   VAL   = (u16*)(ws + 1158400 + 3ull * 33554432ull);

  k_prep<<<316, 256, 0, stream>>>(s, a, Wsa, Wse, Wsl, Wk, Wv, Wc1,
                                  flag, part, Wsa_t, Wse_t, Wp_t, Wc1t);
  k_fin<<<NA, 256, 0, stream>>>(part, mst_g);
  k_enc5<<<dim3(BATCH / 64, NA), 256, 0, stream>>>(s, a, Wsa_t, bsa, Wse_t, bse, Wp_t, bv,
                                                   mst_g, flag, SEb, SEL, KEY, VAL);
  k_attn<<<BATCH / 8, 256, 0, stream>>>(SEL, KEY, VAL);
  k_critic<<<dim3(BATCH / 128, NA), 256, 0, stream>>>(SEb, SEL, a, Wc1t, bc1, Wc2, bc2, flag, d_out);
}